// Round 6
// baseline (279.127 us; speedup 1.0000x reference)
//
#include <hip/hip_runtime.h>

#define N_NODES 50000
#define N_EDGES 800000
#define IN_CH 128
#define OUT_CH 64
#define HEADS 4
#define HC 256  // HEADS*OUT_CH
#define NEG_SLOPE 0.2f
#define LOGIT_BLOCKS 3125  // 16 nodes/block
#define CNT_BLOCKS 782     // 1024 edges/block
#define GEMM_BLOCKS 782    // 64 rows/block
#define SCAT_BLOCKS 3125   // 256 edges/block
#define SCAN_BLOCKS 49     // 1024 nodes/block

// ---------------- workspace layout (bytes) ----------------
#define HB_OFF       0UL          // bf16 h: 25,600,000
#define WSW_OFF      25600000UL   // swizzled bf16 W: 65,536
#define ASRC_OFF     25665536UL   // 800,000
#define ADST_OFF     26465536UL   // 800,000
#define COUNTS_OFF   27265536UL   // 200,000
#define OFFSETS_OFF  27465536UL   // 200,000
#define CURSOR_OFF   27665536UL   // 200,000
#define BSUMS_OFF    27865536UL   // 1,024
#define WSV_OFF      27866560UL   // 2,048  (W @ att_src, [128][4])
#define WDV_OFF      27868608UL   // 2,048  (W @ att_dst, [128][4])
#define REC_OFF      27870656UL   // 32B/edge records: 25,600,000
// total ≈ 53.5 MB

typedef __attribute__((ext_vector_type(8))) short short8;
typedef __attribute__((ext_vector_type(4))) float f32x4;

__device__ __forceinline__ unsigned short f2bf(float f) {
  unsigned int u = __float_as_uint(f);
  unsigned int r = (u + 0x7fffu + ((u >> 16) & 1u)) >> 16;
  return (unsigned short)r;
}
__device__ __forceinline__ float bf2f_lo(unsigned int u) {
  return __uint_as_float(u << 16);
}
__device__ __forceinline__ float bf2f_hi(unsigned int u) {
  return __uint_as_float(u & 0xffff0000u);
}
__device__ __forceinline__ float lrelu(float e) {
  return e > 0.f ? e : NEG_SLOPE * e;
}

// ---------------- init: W swizzle | att projection | zero counts ----------------
__global__ __launch_bounds__(256) void init_k(const float* __restrict__ W,
                                              const float* __restrict__ att_s,
                                              const float* __restrict__ att_d,
                                              unsigned short* __restrict__ Wsw,
                                              float* __restrict__ wsv,
                                              float* __restrict__ wdv,
                                              int* __restrict__ counts) {
  if (blockIdx.x < 16) {  // W -> bf16 B-frag order for mfma_16x16x32_bf16
    int idx = blockIdx.x * 256 + threadIdx.x;  // 0..4095
    int l = idx & 63;
    int kc = (idx >> 6) & 3;
    int t = idx >> 8;
    int kbase = kc * 32 + (l >> 4) * 8;
    int col = t * 16 + (l & 15);
    unsigned int p[4];
#pragma unroll
    for (int j = 0; j < 4; ++j) {
      unsigned int lo = f2bf(W[(size_t)(kbase + 2 * j) * HC + col]);
      unsigned int hi = f2bf(W[(size_t)(kbase + 2 * j + 1) * HC + col]);
      p[j] = lo | (hi << 16);
    }
    *(uint4*)(Wsw + (size_t)idx * 8) = make_uint4(p[0], p[1], p[2], p[3]);
  } else if (blockIdx.x == 16) {  // wsv[k][hd] = sum_c W[k][hd*64+c]*att_s[hd*64+c]
    int t = threadIdx.x;
    int k = t >> 1;
    int side = t & 1;
    const float* att = side ? att_d : att_s;
    float v[4] = {0.f, 0.f, 0.f, 0.f};
    const float* wr = W + (size_t)k * HC;
    for (int c = 0; c < 64; ++c) {
#pragma unroll
      for (int hd = 0; hd < 4; ++hd) v[hd] = fmaf(wr[hd * 64 + c], att[hd * 64 + c], v[hd]);
    }
    float* dp = side ? wdv : wsv;
    *(float4*)(dp + k * 4) = make_float4(v[0], v[1], v[2], v[3]);
  } else {
    int i = (blockIdx.x - 17) * 256 + threadIdx.x;
    if (i < N_NODES) counts[i] = 0;
  }
}

// ---------------- logits (from x directly) + degree count ----------------
__global__ __launch_bounds__(256) void logits_count(const float* __restrict__ x,
                                                    const float* __restrict__ wsv,
                                                    const float* __restrict__ wdv,
                                                    const int* __restrict__ dstv,
                                                    float* __restrict__ a_src,
                                                    float* __restrict__ a_dst,
                                                    int* __restrict__ counts) {
  if (blockIdx.x >= LOGIT_BLOCKS) {  // count role
    int base = (blockIdx.x - LOGIT_BLOCKS) * 1024 + threadIdx.x;
#pragma unroll
    for (int k = 0; k < 4; ++k) {
      int e = base + k * 256;
      if (e < N_EDGES) atomicAdd(&counts[dstv[e]], 1);
    }
    return;
  }
  const int t = threadIdx.x;
  const int nl = t >> 4;    // node within block 0..15
  const int lane = t & 15;  // k-slice
  const int node = blockIdx.x * 16 + nl;  // 3125*16 = 50000 exact
  const float* xr = x + (size_t)node * IN_CH + lane * 8;
  float4 x0 = *(const float4*)xr;
  float4 x1 = *(const float4*)(xr + 4);
  float xs[8] = {x0.x, x0.y, x0.z, x0.w, x1.x, x1.y, x1.z, x1.w};
  float as[4] = {0.f, 0.f, 0.f, 0.f}, ad[4] = {0.f, 0.f, 0.f, 0.f};
#pragma unroll
  for (int j = 0; j < 8; ++j) {
    int k = lane * 8 + j;
    float4 wv = *(const float4*)(wsv + k * 4);
    float4 dv = *(const float4*)(wdv + k * 4);
    as[0] = fmaf(xs[j], wv.x, as[0]); as[1] = fmaf(xs[j], wv.y, as[1]);
    as[2] = fmaf(xs[j], wv.z, as[2]); as[3] = fmaf(xs[j], wv.w, as[3]);
    ad[0] = fmaf(xs[j], dv.x, ad[0]); ad[1] = fmaf(xs[j], dv.y, ad[1]);
    ad[2] = fmaf(xs[j], dv.z, ad[2]); ad[3] = fmaf(xs[j], dv.w, ad[3]);
  }
#pragma unroll
  for (int mask = 1; mask < 16; mask <<= 1) {
#pragma unroll
    for (int hd = 0; hd < 4; ++hd) {
      as[hd] += __shfl_xor(as[hd], mask);
      ad[hd] += __shfl_xor(ad[hd], mask);
    }
  }
  if (lane == 0) *(float4*)(a_src + node * 4) = make_float4(as[0], as[1], as[2], as[3]);
  if (lane == 1) *(float4*)(a_dst + node * 4) = make_float4(ad[0], ad[1], ad[2], ad[3]);
}

// ---------------- scan ----------------
__global__ __launch_bounds__(256) void scan1(const int* __restrict__ counts,
                                             int* __restrict__ offsets,
                                             int* __restrict__ bsums) {
  __shared__ int sd[256];
  const int base = blockIdx.x * 1024;
  const int t = threadIdx.x;
  int v[4];
  int tsum = 0;
#pragma unroll
  for (int k = 0; k < 4; ++k) {
    int i = base + t * 4 + k;
    v[k] = (i < N_NODES) ? counts[i] : 0;
    tsum += v[k];
  }
  sd[t] = tsum;
  __syncthreads();
  for (int off = 1; off < 256; off <<= 1) {
    int xval = (t >= off) ? sd[t - off] : 0;
    __syncthreads();
    sd[t] += xval;
    __syncthreads();
  }
  int excl = sd[t] - tsum;
  int run = excl;
#pragma unroll
  for (int k = 0; k < 4; ++k) {
    int i = base + t * 4 + k;
    if (i < N_NODES) offsets[i] = run;
    run += v[k];
  }
  if (t == 255) bsums[blockIdx.x] = sd[255];
}

// scan2+scan3 fused: every block redundantly wave-scans the 49 block sums.
__global__ __launch_bounds__(256) void scan23(int* __restrict__ offsets,
                                              const int* __restrict__ bsums,
                                              int* __restrict__ cursor) {
  __shared__ int s_add;
  if (threadIdx.x < 64) {
    int lane = threadIdx.x;
    int v = (lane < SCAN_BLOCKS) ? bsums[lane] : 0;
#pragma unroll
    for (int o = 1; o < 64; o <<= 1) {
      int t = __shfl_up(v, o);
      if (lane >= o) v += t;
    }
    int b = blockIdx.x;
    int pre = (b == 0) ? 0 : __shfl(v, b - 1);
    if (lane == 0) s_add = pre;
  }
  __syncthreads();
  const int add = s_add;
  const int base = blockIdx.x * 1024;
  const int t = threadIdx.x;
#pragma unroll
  for (int k = 0; k < 4; ++k) {
    int i = base + t * 4 + k;
    if (i < N_NODES) {
      int o = offsets[i] + add;
      offsets[i] = o;
      cursor[i] = o;
    }
  }
}

// ---------------- GEMM (MFMA) + scatter, co-dispatched ----------------
// gemm role: blocks 0..781, wave-private LDS transpose in 2 col-chunks (32 KB).
// scatter role: blocks 782.., one edge/thread, writes 32B {src, ex4} records.
__global__ __launch_bounds__(256) void gemm_scatter(const float* __restrict__ x,
                                                    const unsigned short* __restrict__ Wsw,
                                                    const int* __restrict__ srcv,
                                                    const int* __restrict__ dstv,
                                                    const float* __restrict__ a_src,
                                                    const float* __restrict__ a_dst,
                                                    int* __restrict__ cursor,
                                                    char* __restrict__ rec,
                                                    unsigned short* __restrict__ hb) {
  __shared__ float Cs[4][16][128];  // 32 KB, per-wave slices, XOR-swizzled

  if (blockIdx.x >= GEMM_BLOCKS) {  // ---- scatter role ----
    int e = (blockIdx.x - GEMM_BLOCKS) * 256 + threadIdx.x;  // 3125*256 = 800000
    int s = srcv[e];
    int d = dstv[e];
    float4 as = *(const float4*)(a_src + s * 4);
    float4 ad = *(const float4*)(a_dst + d * 4);
    float4 ex;
    ex.x = __expf(lrelu(as.x + ad.x));
    ex.y = __expf(lrelu(as.y + ad.y));
    ex.z = __expf(lrelu(as.z + ad.z));
    ex.w = __expf(lrelu(as.w + ad.w));
    int pos = atomicAdd(&cursor[d], 1);
    char* rp = rec + (size_t)pos * 32;
    *(uint4*)rp = make_uint4((unsigned)s, __float_as_uint(ex.x),
                             __float_as_uint(ex.y), __float_as_uint(ex.z));
    *(unsigned*)(rp + 16) = __float_as_uint(ex.w);
    return;
  }

  const int wave = threadIdx.x >> 6;
  const int l = threadIdx.x & 63;
  const int q = l >> 4;
  const int m = l & 15;
  const int mrow = blockIdx.x * 64 + wave * 16 + m;
  const bool mvalid = mrow < N_NODES;
  const int rc = mvalid ? mrow : (N_NODES - 1);

  short8 a[4];
  const float* xr = x + (size_t)rc * IN_CH + q * 8;
#pragma unroll
  for (int kc = 0; kc < 4; ++kc) {
    float4 u = *(const float4*)(xr + kc * 32);
    float4 v = *(const float4*)(xr + kc * 32 + 4);
    short8 t;
    t[0] = (short)f2bf(u.x); t[1] = (short)f2bf(u.y);
    t[2] = (short)f2bf(u.z); t[3] = (short)f2bf(u.w);
    t[4] = (short)f2bf(v.x); t[5] = (short)f2bf(v.y);
    t[6] = (short)f2bf(v.z); t[7] = (short)f2bf(v.w);
    a[kc] = t;
  }

  unsigned short* hrow = hb + (size_t)mrow * HC + q * 64;
  const int sw = m << 2;
#pragma unroll
  for (int chunk = 0; chunk < 2; ++chunk) {
#pragma unroll
    for (int t8 = 0; t8 < 8; ++t8) {
      const int t = chunk * 8 + t8;
      f32x4 acc = {0.f, 0.f, 0.f, 0.f};
#pragma unroll
      for (int kc = 0; kc < 4; ++kc) {
        short8 b = *(const short8*)(Wsw + ((size_t)(t * 4 + kc) * 64 + l) * 8);
        acc = __builtin_amdgcn_mfma_f32_16x16x32_bf16(a[kc], b, acc, 0, 0, 0);
      }
#pragma unroll
      for (int r = 0; r < 4; ++r) {
        int row = q * 4 + r;
        Cs[wave][row][(t8 * 16 + m) ^ (row << 2)] = acc[r];
      }
    }
    // wave-private readback: lanes whose head lives in this chunk
    if ((q >> 1) == chunk && mvalid) {
      const int cb = (q & 1) * 64;  // local col base
#pragma unroll
      for (int i = 0; i < 8; ++i) {
        int c0 = cb + i * 8;
        float4 c1 = *(const float4*)&Cs[wave][m][(c0) ^ sw];
        float4 c2 = *(const float4*)&Cs[wave][m][(c0 + 4) ^ sw];
        uint4 p;
        p.x = (unsigned int)f2bf(c1.x) | ((unsigned int)f2bf(c1.y) << 16);
        p.y = (unsigned int)f2bf(c1.z) | ((unsigned int)f2bf(c1.w) << 16);
        p.z = (unsigned int)f2bf(c2.x) | ((unsigned int)f2bf(c2.y) << 16);
        p.w = (unsigned int)f2bf(c2.z) | ((unsigned int)f2bf(c2.w) << 16);
        *(uint4*)(hrow + i * 8) = p;
      }
    }
  }
}

// ---------------- aggregate: R4 layout (2 groups x 8ch), 32B records ----------------
__global__ __launch_bounds__(256) void aggregate(const unsigned short* __restrict__ hb,
                                                 const float* __restrict__ a_src,
                                                 const float* __restrict__ a_dst,
                                                 const int* __restrict__ counts,
                                                 const int* __restrict__ offsets,
                                                 const char* __restrict__ rec,
                                                 const float* __restrict__ bias,
                                                 float* __restrict__ out) {
  const int node = blockIdx.x * 4 + (threadIdx.x >> 6);
  const int l = threadIdx.x & 63;
  const int g = l >> 5;
  const int q = l & 31;
  const int hd = q >> 3;
  const int c0 = q * 8;
  const int deg = counts[node];
  const int start = offsets[node];

  float denom = 0.f;
  float acc[8] = {0.f, 0.f, 0.f, 0.f, 0.f, 0.f, 0.f, 0.f};
#pragma unroll 4
  for (int j = 0; j + g < deg; j += 2) {
    int idx = start + j + g;
    const char* rp = rec + (size_t)idx * 32;
    int s = *(const int*)rp;
    float ex = *(const float*)(rp + 4 + hd * 4);
    uint4 hv = *(const uint4*)(hb + (size_t)s * HC + c0);
    denom += ex;
    acc[0] += bf2f_lo(hv.x) * ex;
    acc[1] += bf2f_hi(hv.x) * ex;
    acc[2] += bf2f_lo(hv.y) * ex;
    acc[3] += bf2f_hi(hv.y) * ex;
    acc[4] += bf2f_lo(hv.z) * ex;
    acc[5] += bf2f_hi(hv.z) * ex;
    acc[6] += bf2f_lo(hv.w) * ex;
    acc[7] += bf2f_hi(hv.w) * ex;
  }
  // combine the two edge-parity groups
  denom += __shfl_xor(denom, 32);
#pragma unroll
  for (int k = 0; k < 8; ++k) acc[k] += __shfl_xor(acc[k], 32);

  // self-loop (after combine; only g==0 lanes' values are used)
  float es = a_src[node * HEADS + hd] + a_dst[node * HEADS + hd];
  float ex_self = __expf(lrelu(es));
  denom += ex_self;
  uint4 hs = *(const uint4*)(hb + (size_t)node * HC + c0);
  acc[0] += bf2f_lo(hs.x) * ex_self;
  acc[1] += bf2f_hi(hs.x) * ex_self;
  acc[2] += bf2f_lo(hs.y) * ex_self;
  acc[3] += bf2f_hi(hs.y) * ex_self;
  acc[4] += bf2f_lo(hs.z) * ex_self;
  acc[5] += bf2f_hi(hs.z) * ex_self;
  acc[6] += bf2f_lo(hs.w) * ex_self;
  acc[7] += bf2f_hi(hs.w) * ex_self;

  if (g == 0) {
    float inv = 1.f / (denom + 1e-16f);
    float4 b1 = *(const float4*)(bias + c0);
    float4 b2 = *(const float4*)(bias + c0 + 4);
    float4 o1 = make_float4(acc[0] * inv + b1.x, acc[1] * inv + b1.y,
                            acc[2] * inv + b1.z, acc[3] * inv + b1.w);
    float4 o2 = make_float4(acc[4] * inv + b2.x, acc[5] * inv + b2.y,
                            acc[6] * inv + b2.z, acc[7] * inv + b2.w);
    *(float4*)(out + (size_t)node * HC + c0) = o1;
    *(float4*)(out + (size_t)node * HC + c0 + 4) = o2;
  }
}

extern "C" void kernel_launch(void* const* d_in, const int* in_sizes, int n_in,
                              void* d_out, int out_size, void* d_ws, size_t ws_size,
                              hipStream_t stream) {
  const float* x     = (const float*)d_in[0];
  const int*   ei    = (const int*)d_in[1];
  const float* W     = (const float*)d_in[2];
  const float* att_s = (const float*)d_in[3];
  const float* att_d = (const float*)d_in[4];
  const float* bias  = (const float*)d_in[5];
  float* out = (float*)d_out;

  char* ws = (char*)d_ws;
  unsigned short* hb  = (unsigned short*)(ws + HB_OFF);
  unsigned short* Wsw = (unsigned short*)(ws + WSW_OFF);
  float* a_src  = (float*)(ws + ASRC_OFF);
  float* a_dst  = (float*)(ws + ADST_OFF);
  int* counts   = (int*)(ws + COUNTS_OFF);
  int* offsets  = (int*)(ws + OFFSETS_OFF);
  int* cursor   = (int*)(ws + CURSOR_OFF);
  int* bsums    = (int*)(ws + BSUMS_OFF);
  float* wsv    = (float*)(ws + WSV_OFF);
  float* wdv    = (float*)(ws + WDV_OFF);
  char* rec     = (char*)(ws + REC_OFF);

  const int* src = ei;             // edge_index[0]
  const int* dst = ei + N_EDGES;   // edge_index[1]

  init_k<<<17 + 196, 256, 0, stream>>>(W, att_s, att_d, Wsw, wsv, wdv, counts);
  logits_count<<<LOGIT_BLOCKS + CNT_BLOCKS, 256, 0, stream>>>(
      x, wsv, wdv, dst, a_src, a_dst, counts);
  scan1<<<SCAN_BLOCKS, 256, 0, stream>>>(counts, offsets, bsums);
  scan23<<<SCAN_BLOCKS, 256, 0, stream>>>(offsets, bsums, cursor);
  gemm_scatter<<<GEMM_BLOCKS + SCAT_BLOCKS, 256, 0, stream>>>(
      x, Wsw, src, dst, a_src, a_dst, cursor, rec, hb);
  aggregate<<<12500, 256, 0, stream>>>(hb, a_src, a_dst, counts, offsets, rec, bias, out);
}

// Round 7
// 258.436 us; speedup vs baseline: 1.0801x; 1.0801x over previous
//
#include <hip/hip_runtime.h>

#define N_NODES 50000
#define N_EDGES 800000
#define IN_CH 128
#define OUT_CH 64
#define HEADS 4
#define HC 256  // HEADS*OUT_CH
#define NEG_SLOPE 0.2f
#define GEMM_BLOCKS 782    // 64 rows/block
#define CNT_BLOCKS 782     // 1024 edges/block
#define SCAT_BLOCKS 3125   // 256 edges/block
#define SCAN_BLOCKS 49     // 1024 nodes/block

// ---------------- workspace layout (bytes) ----------------
#define HB_OFF       0UL          // bf16 h (PERMUTED channel order): 25,600,000
#define WSW_OFF      25600000UL   // swizzled bf16 W: 65,536
#define ASRC_OFF     25665536UL   // 800,000
#define ADST_OFF     26465536UL   // 800,000
#define COUNTS_OFF   27265536UL   // 200,000
#define OFFSETS_OFF  27465536UL   // 200,000
#define CURSOR_OFF   27665536UL   // 200,000
#define BSUMS_OFF    27865536UL   // 1,024
#define ATTSP_OFF    27866560UL   // 1,024 (permuted att_src)
#define ATTDP_OFF    27867584UL   // 1,024 (permuted att_dst)
#define REC_OFF      27868608UL   // 32B/edge records: 25,600,000
// total ≈ 53.5 MB

typedef __attribute__((ext_vector_type(8))) short short8;
typedef __attribute__((ext_vector_type(4))) float f32x4;

__device__ __forceinline__ unsigned short f2bf(float f) {
  unsigned int u = __float_as_uint(f);
  unsigned int r = (u + 0x7fffu + ((u >> 16) & 1u)) >> 16;
  return (unsigned short)r;
}
__device__ __forceinline__ unsigned int packbf(float a, float b) {
  return (unsigned int)f2bf(a) | ((unsigned int)f2bf(b) << 16);
}
__device__ __forceinline__ float bf2f_lo(unsigned int u) {
  return __uint_as_float(u << 16);
}
__device__ __forceinline__ float bf2f_hi(unsigned int u) {
  return __uint_as_float(u & 0xffff0000u);
}
__device__ __forceinline__ float lrelu(float e) {
  return e > 0.f ? e : NEG_SLOPE * e;
}

// ---------------- init: W swizzle | att permute | zero counts ----------------
// hb channel permutation: position p = 64q + 4t + r  <->  channel c = 16t + 4q + r
__global__ __launch_bounds__(256) void init_k(const float* __restrict__ W,
                                              const float* __restrict__ att_s,
                                              const float* __restrict__ att_d,
                                              unsigned short* __restrict__ Wsw,
                                              float* __restrict__ att_sp,
                                              float* __restrict__ att_dp,
                                              int* __restrict__ counts) {
  if (blockIdx.x < 16) {  // W -> A-frag order for mfma_16x16x32_bf16 (ch-tile t, k-chunk kc)
    int idx = blockIdx.x * 256 + threadIdx.x;  // 0..4095
    int l = idx & 63;
    int kc = (idx >> 6) & 3;
    int t = idx >> 8;
    int kbase = kc * 32 + (l >> 4) * 8;
    int col = t * 16 + (l & 15);
    unsigned int p[4];
#pragma unroll
    for (int j = 0; j < 4; ++j) {
      unsigned int lo = f2bf(W[(size_t)(kbase + 2 * j) * HC + col]);
      unsigned int hi = f2bf(W[(size_t)(kbase + 2 * j + 1) * HC + col]);
      p[j] = lo | (hi << 16);
    }
    *(uint4*)(Wsw + (size_t)idx * 8) = make_uint4(p[0], p[1], p[2], p[3]);
  } else if (blockIdx.x == 16) {  // att vectors into permuted order
    int p = threadIdx.x;
    int q = p >> 6, t = (p >> 2) & 15, r = p & 3;
    int c = t * 16 + q * 4 + r;
    att_sp[p] = att_s[c];
    att_dp[p] = att_d[c];
  } else {
    int i = (blockIdx.x - 17) * 256 + threadIdx.x;
    if (i < N_NODES) counts[i] = 0;
  }
}

// ---------------- MFMA GEMM (C^T, no LDS) + fused logits, count piggybacked ----------------
__global__ __launch_bounds__(256) void gemm_count(const float* __restrict__ x,
                                                  const unsigned short* __restrict__ Wsw,
                                                  const float* __restrict__ att_sp,
                                                  const float* __restrict__ att_dp,
                                                  const int* __restrict__ dstv,
                                                  unsigned short* __restrict__ hb,
                                                  float* __restrict__ a_src,
                                                  float* __restrict__ a_dst,
                                                  int* __restrict__ counts) {
  if (blockIdx.x >= GEMM_BLOCKS) {  // ---- count role ----
    int base = (blockIdx.x - GEMM_BLOCKS) * 1024 + threadIdx.x;
#pragma unroll
    for (int k = 0; k < 4; ++k) {
      int e = base + k * 256;
      if (e < N_EDGES) atomicAdd(&counts[dstv[e]], 1);
    }
    return;
  }

  const int wave = threadIdx.x >> 6;
  const int l = threadIdx.x & 63;
  const int q = l >> 4;   // k-slice / channel-quarter
  const int m = l & 15;   // node within wave
  const int node = blockIdx.x * 64 + wave * 16 + m;
  const bool valid = node < N_NODES;
  const int rc = valid ? node : (N_NODES - 1);

  // B-frags: x[rc][kc*32 + q*8 .. +7] as bf16
  short8 xf[4];
  const float* xr = x + (size_t)rc * IN_CH + q * 8;
#pragma unroll
  for (int kc = 0; kc < 4; ++kc) {
    float4 u = *(const float4*)(xr + kc * 32);
    float4 v = *(const float4*)(xr + kc * 32 + 4);
    short8 t;
    t[0] = (short)f2bf(u.x); t[1] = (short)f2bf(u.y);
    t[2] = (short)f2bf(u.z); t[3] = (short)f2bf(u.w);
    t[4] = (short)f2bf(v.x); t[5] = (short)f2bf(v.y);
    t[6] = (short)f2bf(v.z); t[7] = (short)f2bf(v.w);
    xf[kc] = t;
  }

  // acc[t][r]: channel c = 16t + 4q + r of this lane's node
  f32x4 acc[16];
#pragma unroll
  for (int t = 0; t < 16; ++t) acc[t] = (f32x4){0.f, 0.f, 0.f, 0.f};
#pragma unroll
  for (int t = 0; t < 16; ++t) {
#pragma unroll
    for (int kc = 0; kc < 4; ++kc) {
      short8 w = *(const short8*)(Wsw + ((size_t)(t * 4 + kc) * 64 + l) * 8);
      acc[t] = __builtin_amdgcn_mfma_f32_16x16x32_bf16(w, xf[kc], acc[t], 0, 0, 0);
    }
  }

  // fused logits: per-head partials over this lane's 64 channels (permuted att)
  float hs[4] = {0.f, 0.f, 0.f, 0.f}, hd[4] = {0.f, 0.f, 0.f, 0.f};
#pragma unroll
  for (int t = 0; t < 16; ++t) {
    int head = t >> 2;
    float4 av = *(const float4*)(att_sp + q * 64 + t * 4);
    float4 dv = *(const float4*)(att_dp + q * 64 + t * 4);
    hs[head] += acc[t][0] * av.x + acc[t][1] * av.y + acc[t][2] * av.z + acc[t][3] * av.w;
    hd[head] += acc[t][0] * dv.x + acc[t][1] * dv.y + acc[t][2] * dv.z + acc[t][3] * dv.w;
  }
#pragma unroll
  for (int head = 0; head < 4; ++head) {
    hs[head] += __shfl_xor(hs[head], 16);
    hs[head] += __shfl_xor(hs[head], 32);
    hd[head] += __shfl_xor(hd[head], 16);
    hd[head] += __shfl_xor(hd[head], 32);
  }
  if (valid && q == 0) {
    *(float4*)(a_src + node * 4) = make_float4(hs[0], hs[1], hs[2], hs[3]);
    *(float4*)(a_dst + node * 4) = make_float4(hd[0], hd[1], hd[2], hd[3]);
  }

  // store hb in permuted order: lane covers positions [64q, 64q+64)
  if (valid) {
    unsigned short* hp = hb + (size_t)node * HC + q * 64;
#pragma unroll
    for (int t = 0; t < 16; t += 2) {
      uint4 P;
      P.x = packbf(acc[t][0], acc[t][1]);
      P.y = packbf(acc[t][2], acc[t][3]);
      P.z = packbf(acc[t + 1][0], acc[t + 1][1]);
      P.w = packbf(acc[t + 1][2], acc[t + 1][3]);
      *(uint4*)(hp + t * 4) = P;
    }
  }
}

// ---------------- scan ----------------
__global__ __launch_bounds__(256) void scan1(const int* __restrict__ counts,
                                             int* __restrict__ offsets,
                                             int* __restrict__ bsums) {
  __shared__ int sd[256];
  const int base = blockIdx.x * 1024;
  const int t = threadIdx.x;
  int v[4];
  int tsum = 0;
#pragma unroll
  for (int k = 0; k < 4; ++k) {
    int i = base + t * 4 + k;
    v[k] = (i < N_NODES) ? counts[i] : 0;
    tsum += v[k];
  }
  sd[t] = tsum;
  __syncthreads();
  for (int off = 1; off < 256; off <<= 1) {
    int xval = (t >= off) ? sd[t - off] : 0;
    __syncthreads();
    sd[t] += xval;
    __syncthreads();
  }
  int excl = sd[t] - tsum;
  int run = excl;
#pragma unroll
  for (int k = 0; k < 4; ++k) {
    int i = base + t * 4 + k;
    if (i < N_NODES) offsets[i] = run;
    run += v[k];
  }
  if (t == 255) bsums[blockIdx.x] = sd[255];
}

__global__ __launch_bounds__(256) void scan23(int* __restrict__ offsets,
                                              const int* __restrict__ bsums,
                                              int* __restrict__ cursor) {
  __shared__ int s_add;
  if (threadIdx.x < 64) {
    int lane = threadIdx.x;
    int v = (lane < SCAN_BLOCKS) ? bsums[lane] : 0;
#pragma unroll
    for (int o = 1; o < 64; o <<= 1) {
      int t = __shfl_up(v, o);
      if (lane >= o) v += t;
    }
    int b = blockIdx.x;
    int pre = (b == 0) ? 0 : __shfl(v, b - 1);
    if (lane == 0) s_add = pre;
  }
  __syncthreads();
  const int add = s_add;
  const int base = blockIdx.x * 1024;
  const int t = threadIdx.x;
#pragma unroll
  for (int k = 0; k < 4; ++k) {
    int i = base + t * 4 + k;
    if (i < N_NODES) {
      int o = offsets[i] + add;
      offsets[i] = o;
      cursor[i] = o;
    }
  }
}

// ---------------- scatter: standalone, one 32B record {src, ex4} per edge ----------------
__global__ __launch_bounds__(256) void scatter_k(const int* __restrict__ src,
                                                 const int* __restrict__ dst,
                                                 const float* __restrict__ a_src,
                                                 const float* __restrict__ a_dst,
                                                 int* __restrict__ cursor,
                                                 char* __restrict__ rec) {
  int e = blockIdx.x * 256 + threadIdx.x;  // 3125*256 = 800000 exact
  int s = src[e];
  int d = dst[e];
  float4 as = *(const float4*)(a_src + s * 4);
  float4 ad = *(const float4*)(a_dst + d * 4);
  float4 ex;
  ex.x = __expf(lrelu(as.x + ad.x));
  ex.y = __expf(lrelu(as.y + ad.y));
  ex.z = __expf(lrelu(as.z + ad.z));
  ex.w = __expf(lrelu(as.w + ad.w));
  int pos = atomicAdd(&cursor[d], 1);
  char* rp = rec + (size_t)pos * 32;
  *(uint4*)rp = make_uint4((unsigned)s, __float_as_uint(ex.x),
                           __float_as_uint(ex.y), __float_as_uint(ex.z));
  *(unsigned*)(rp + 16) = __float_as_uint(ex.w);
}

// ---------------- aggregate: permuted hb, 2 edge groups x 8 positions ----------------
__global__ __launch_bounds__(256) void aggregate(const unsigned short* __restrict__ hb,
                                                 const float* __restrict__ a_src,
                                                 const float* __restrict__ a_dst,
                                                 const int* __restrict__ counts,
                                                 const int* __restrict__ offsets,
                                                 const char* __restrict__ rec,
                                                 const float* __restrict__ bias,
                                                 float* __restrict__ out) {
  const int node = blockIdx.x * 4 + (threadIdx.x >> 6);
  const int l = threadIdx.x & 63;
  const int g = l >> 5;   // edge parity
  const int q = l & 31;   // position slice: positions q*8 .. q*8+7
  // position p = 64*qq + 4t + r <-> channel 16t + 4qq + r
  const int qq = q >> 3;
  const int t0 = (q & 7) * 2;
  const int hd = (q & 7) >> 1;       // head of both tiles t0, t0+1
  const int c1 = t0 * 16 + qq * 4;   // canonical channels of acc[0..3]
  const int c2 = c1 + 16;            // canonical channels of acc[4..7]
  const int p0 = q * 8;
  const int deg = counts[node];
  const int start = offsets[node];

  float denom = 0.f;
  float acc[8] = {0.f, 0.f, 0.f, 0.f, 0.f, 0.f, 0.f, 0.f};
#pragma unroll 4
  for (int j = 0; j + g < deg; j += 2) {
    int idx = start + j + g;
    const char* rp = rec + (size_t)idx * 32;
    int s = *(const int*)rp;
    float ex = *(const float*)(rp + 4 + hd * 4);
    uint4 hv = *(const uint4*)(hb + (size_t)s * HC + p0);
    denom += ex;
    acc[0] += bf2f_lo(hv.x) * ex;
    acc[1] += bf2f_hi(hv.x) * ex;
    acc[2] += bf2f_lo(hv.y) * ex;
    acc[3] += bf2f_hi(hv.y) * ex;
    acc[4] += bf2f_lo(hv.z) * ex;
    acc[5] += bf2f_hi(hv.z) * ex;
    acc[6] += bf2f_lo(hv.w) * ex;
    acc[7] += bf2f_hi(hv.w) * ex;
  }
  denom += __shfl_xor(denom, 32);
#pragma unroll
  for (int k = 0; k < 8; ++k) acc[k] += __shfl_xor(acc[k], 32);

  // self-loop
  float es = a_src[node * HEADS + hd] + a_dst[node * HEADS + hd];
  float ex_self = __expf(lrelu(es));
  denom += ex_self;
  uint4 hs = *(const uint4*)(hb + (size_t)node * HC + p0);
  acc[0] += bf2f_lo(hs.x) * ex_self;
  acc[1] += bf2f_hi(hs.x) * ex_self;
  acc[2] += bf2f_lo(hs.y) * ex_self;
  acc[3] += bf2f_hi(hs.y) * ex_self;
  acc[4] += bf2f_lo(hs.z) * ex_self;
  acc[5] += bf2f_hi(hs.z) * ex_self;
  acc[6] += bf2f_lo(hs.w) * ex_self;
  acc[7] += bf2f_hi(hs.w) * ex_self;

  if (g == 0) {
    float inv = 1.f / (denom + 1e-16f);
    float4 b1 = *(const float4*)(bias + c1);
    float4 b2 = *(const float4*)(bias + c2);
    float4 o1 = make_float4(acc[0] * inv + b1.x, acc[1] * inv + b1.y,
                            acc[2] * inv + b1.z, acc[3] * inv + b1.w);
    float4 o2 = make_float4(acc[4] * inv + b2.x, acc[5] * inv + b2.y,
                            acc[6] * inv + b2.z, acc[7] * inv + b2.w);
    *(float4*)(out + (size_t)node * HC + c1) = o1;
    *(float4*)(out + (size_t)node * HC + c2) = o2;
  }
}

extern "C" void kernel_launch(void* const* d_in, const int* in_sizes, int n_in,
                              void* d_out, int out_size, void* d_ws, size_t ws_size,
                              hipStream_t stream) {
  const float* x     = (const float*)d_in[0];
  const int*   ei    = (const int*)d_in[1];
  const float* W     = (const float*)d_in[2];
  const float* att_s = (const float*)d_in[3];
  const float* att_d = (const float*)d_in[4];
  const float* bias  = (const float*)d_in[5];
  float* out = (float*)d_out;

  char* ws = (char*)d_ws;
  unsigned short* hb  = (unsigned short*)(ws + HB_OFF);
  unsigned short* Wsw = (unsigned short*)(ws + WSW_OFF);
  float* a_src  = (float*)(ws + ASRC_OFF);
  float* a_dst  = (float*)(ws + ADST_OFF);
  int* counts   = (int*)(ws + COUNTS_OFF);
  int* offsets  = (int*)(ws + OFFSETS_OFF);
  int* cursor   = (int*)(ws + CURSOR_OFF);
  int* bsums    = (int*)(ws + BSUMS_OFF);
  float* att_sp = (float*)(ws + ATTSP_OFF);
  float* att_dp = (float*)(ws + ATTDP_OFF);
  char* rec     = (char*)(ws + REC_OFF);

  const int* src = ei;             // edge_index[0]
  const int* dst = ei + N_EDGES;   // edge_index[1]

  init_k<<<17 + 196, 256, 0, stream>>>(W, att_s, att_d, Wsw, att_sp, att_dp, counts);
  gemm_count<<<GEMM_BLOCKS + CNT_BLOCKS, 256, 0, stream>>>(
      x, Wsw, att_sp, att_dp, dst, hb, a_src, a_dst, counts);
  scan1<<<SCAN_BLOCKS, 256, 0, stream>>>(counts, offsets, bsums);
  scan23<<<SCAN_BLOCKS, 256, 0, stream>>>(offsets, bsums, cursor);
  scatter_k<<<SCAT_BLOCKS, 256, 0, stream>>>(src, dst, a_src, a_dst, cursor, rec);
  aggregate<<<12500, 256, 0, stream>>>(hb, a_src, a_dst, counts, offsets, rec, bias, out);
}